// Round 5
// baseline (2104.332 us; speedup 1.0000x reference)
//
#include <hip/hip_runtime.h>
#include <math.h>

#define N_NODES 100000
#define N_EDGES 1600000
#define ALPHA 0.1f

#define NRANGE 1024              // dst ranges (one block each)
#define RSIZE  98                // nodes per range (1024*98 = 100352 >= N)
#define NTILE  3                 // src tiles
#define TSIZE  33334             // rows per tile (3*33334 = 100002)
#define NPAD   100002            // padded h rows (tile 2 warm reads to 100001)
#define NBKT   (NTILE * NRANGE)  // 3072 buckets, tile-major
#define SORTB  64                // sort blocks (small => long contiguous runs per bucket)
#define TILE_U4 200004           // 33334*96B / 16
#define SLICE_U4 1563            // ceil(200004/128)

typedef unsigned short u16;
typedef unsigned int u32;

__device__ __forceinline__ float bf2f(u16 u) {
    return __uint_as_float(((u32)u) << 16);
}
__device__ __forceinline__ u16 f2bf(float f) {
    u32 b = __float_as_uint(f);
    b += 0x7fff + ((b >> 16) & 1);   // round-to-nearest-even
    return (u16)(b >> 16);
}

// ---------------- lin0: h0 = relu(x @ W0 + b0); writes bf16 x0 AND bf16 h0 ----------------
__global__ __launch_bounds__(256) void lin0_k(const float* __restrict__ x, const float* __restrict__ W0,
                                              const float* __restrict__ b0, u16* __restrict__ x0b,
                                              u16* __restrict__ h0) {
    int t = blockIdx.x * 256 + threadIdx.x;
    if (t >= N_NODES * 48) return;
    int node = t / 48, f = t % 48;
    float v = b0[f]
            + x[node * 3 + 0] * W0[0 * 48 + f]
            + x[node * 3 + 1] * W0[1 * 48 + f]
            + x[node * 3 + 2] * W0[2 * 48 + f];
    v = v > 0.f ? v : 0.f;
    u16 b = f2bf(v);
    x0b[t] = b;
    h0[t] = b;
}

// ---------------- counting sort phase A: per-block histograms over (tile, range) ----------------
__global__ __launch_bounds__(256) void histA_k(const int* __restrict__ src, const int* __restrict__ dst,
                                               int* __restrict__ blockhist) {
    __shared__ int hist[NBKT];
    for (int i = threadIdx.x; i < NBKT; i += 256) hist[i] = 0;
    __syncthreads();
    for (int e = blockIdx.x * 256 + threadIdx.x; e < N_EDGES; e += SORTB * 256) {
        int b = (src[e] / TSIZE) * NRANGE + (dst[e] / RSIZE);
        atomicAdd(&hist[b], 1);
    }
    __syncthreads();
    for (int i = threadIdx.x; i < NBKT; i += 256) blockhist[blockIdx.x * NBKT + i] = hist[i];
}

// ---------------- phase S1: per-bucket exclusive scan across blocks ----------------
__global__ __launch_bounds__(256) void scanS1_k(int* __restrict__ blockhist, int* __restrict__ tot) {
    int b = blockIdx.x * 256 + threadIdx.x;   // 0..NBKT-1
    int run = 0;
#pragma unroll 8
    for (int blk = 0; blk < SORTB; blk++) {
        int t = blockhist[blk * NBKT + b];
        blockhist[blk * NBKT + b] = run;
        run += t;
    }
    tot[b] = run;
}

// ---------------- phase S2: exclusive scan of bucket totals -> bktptr ----------------
__global__ __launch_bounds__(256) void scanS2_k(const int* __restrict__ tot, int* __restrict__ bktptr) {
    __shared__ int sums[256];
    int tid = threadIdx.x;
    int v[NBKT / 256]; int s = 0;
#pragma unroll
    for (int j = 0; j < NBKT / 256; j++) { v[j] = tot[tid * (NBKT / 256) + j]; s += v[j]; }
    sums[tid] = s; __syncthreads();
    for (int off = 1; off < 256; off <<= 1) {
        int t = (tid >= off) ? sums[tid - off] : 0;
        __syncthreads();
        sums[tid] += t;
        __syncthreads();
    }
    int run = (tid > 0) ? sums[tid - 1] : 0;
#pragma unroll
    for (int j = 0; j < NBKT / 256; j++) { bktptr[tid * (NBKT / 256) + j] = run; run += v[j]; }
    if (tid == 255) bktptr[NBKT] = run;
}

// ---------------- phase B: scatter packed edges (src<<8 | dst_local); block-contiguous runs ----
__global__ __launch_bounds__(256) void scatB_k(const int* __restrict__ src, const int* __restrict__ dst,
                                               const int* __restrict__ blockhist, const int* __restrict__ bktptr,
                                               u32* __restrict__ edges) {
    __shared__ int cur[NBKT];
    for (int i = threadIdx.x; i < NBKT; i += 256)
        cur[i] = bktptr[i] + blockhist[blockIdx.x * NBKT + i];
    __syncthreads();
    for (int e = blockIdx.x * 256 + threadIdx.x; e < N_EDGES; e += SORTB * 256) {
        int s = src[e], d = dst[e];
        int r = d / RSIZE;
        int b = (s / TSIZE) * NRANGE + r;
        int dl = d - r * RSIZE;
        int pos = atomicAdd(&cur[b], 1);
        edges[pos] = ((u32)s << 8) | (u32)dl;
    }
}

// ---------------- fused layer: warmed-L2 tiled gather + LDS acc + GCNII combine + matmul + relu ----
// 1024 co-resident blocks (4/CU, 8 waves each). Block owns dst-range (98 nodes), acc in LDS.
// Per tile: stream-warm a 25KB slice (all blocks together put the full tile in every XCD's L2),
// then edge-parallel gather: 8 edges/wave-instr, 8 lanes/edge, 3 dword loads = 96B row.
__global__ __launch_bounds__(512, 8) void layer3_k(const u16* __restrict__ h_in,
                                                   const u32* __restrict__ edges,
                                                   const int* __restrict__ bktptr,
                                                   const u16* __restrict__ x0,
                                                   const float* __restrict__ W, float beta,
                                                   u16* __restrict__ h_out) {
    __shared__ float accs[RSIZE * 48];   // 18816 B
    int tid = threadIdx.x, wave = tid >> 6, lane = tid & 63;
    int range = blockIdx.x;
    for (int i = tid; i < RSIZE * 48; i += 512) accs[i] = 0.f;
    __syncthreads();
    int sub = lane >> 3;   // edge within group: 0..7
    int fl  = lane & 7;    // dword lane within row: 0..7

    for (int tile = 0; tile < NTILE; tile++) {
        // --- warm: coalesced stream of this block's slice -> this XCD's L2 (XCD = blockIdx%8) ---
        {
            const uint4* tb = (const uint4*)(h_in + (size_t)tile * TSIZE * 48);
            int slice = (blockIdx.x >> 3) & 127;
            int start = slice * SLICE_U4;
            int end = start + SLICE_U4; if (end > TILE_U4) end = TILE_U4;
            u32 dummy = 0;
            for (int g = start + tid; g < end; g += 512) {
                uint4 v = tb[g];
                dummy ^= v.x ^ v.y ^ v.z ^ v.w;
            }
            if (dummy == 0xDEADBEEFu) accs[0] = 0.f;   // unprovable-false: keeps the loads
            __syncthreads();
        }
        int b = tile * NRANGE + range;
        int e0 = bktptr[b], e1 = bktptr[b + 1];
        for (int base = e0 + wave * 16; base < e1; base += 8 * 16) {
#pragma unroll
            for (int g = 0; g < 2; g++) {
                int idx = base + g * 8 + sub;
                bool valid = idx < e1;
                int idxc = valid ? idx : (e1 - 1);
                u32 p = __builtin_nontemporal_load(&edges[idxc]);
                int s = (int)(p >> 8);
                int dl = (int)(p & 255u);
                const u32* row = (const u32*)(h_in + s * 48) + fl;
                u32 d0 = row[0], d1 = row[8], d2 = row[16];
                if (valid) {
                    float* arow = accs + dl * 48 + fl * 2;
                    __hip_atomic_fetch_add(&arow[0],  __uint_as_float(d0 << 16),        __ATOMIC_RELAXED, __HIP_MEMORY_SCOPE_WORKGROUP);
                    __hip_atomic_fetch_add(&arow[1],  __uint_as_float(d0 & 0xffff0000u),__ATOMIC_RELAXED, __HIP_MEMORY_SCOPE_WORKGROUP);
                    __hip_atomic_fetch_add(&arow[16], __uint_as_float(d1 << 16),        __ATOMIC_RELAXED, __HIP_MEMORY_SCOPE_WORKGROUP);
                    __hip_atomic_fetch_add(&arow[17], __uint_as_float(d1 & 0xffff0000u),__ATOMIC_RELAXED, __HIP_MEMORY_SCOPE_WORKGROUP);
                    __hip_atomic_fetch_add(&arow[32], __uint_as_float(d2 << 16),        __ATOMIC_RELAXED, __HIP_MEMORY_SCOPE_WORKGROUP);
                    __hip_atomic_fetch_add(&arow[33], __uint_as_float(d2 & 0xffff0000u),__ATOMIC_RELAXED, __HIP_MEMORY_SCOPE_WORKGROUP);
                }
            }
        }
        __syncthreads();
    }

    // --- epilogue: t = (1-a)*agg + a*x0; h_out = relu((1-b)*t + b*(t@W)) ---
    for (int i = wave; i < RSIZE; i += 8) {
        int node = range * RSIZE + i;
        if (node < N_NODES && lane < 48) {
            u16 xb = __builtin_nontemporal_load(&x0[node * 48 + lane]);
            float t = (1.f - ALPHA) * accs[i * 48 + lane] + ALPHA * bf2f(xb);
            accs[i * 48 + lane] = t;   // wave-synchronous write-then-read
            const float4* t4 = (const float4*)&accs[i * 48];
            float s2 = 0.f;
#pragma unroll
            for (int k4 = 0; k4 < 12; k4++) {
                float4 tv = t4[k4];
                s2 += tv.x * W[(4 * k4 + 0) * 48 + lane] + tv.y * W[(4 * k4 + 1) * 48 + lane]
                    + tv.z * W[(4 * k4 + 2) * 48 + lane] + tv.w * W[(4 * k4 + 3) * 48 + lane];
            }
            float o = (1.f - beta) * t + beta * s2;
            u16 ob = f2bf(o > 0.f ? o : 0.f);
            __builtin_nontemporal_store(ob, &h_out[node * 48 + lane]);
        }
    }
}

// ---------------- final: out = log_softmax(h @ W1 + b1) ----------------
__global__ __launch_bounds__(256) void final_k(const u16* __restrict__ h, const float* __restrict__ W1,
                                               const float* __restrict__ b1, float* __restrict__ out) {
    __shared__ float tbuf[4][48];
    int tid = threadIdx.x, wave = tid >> 6, lane = tid & 63;
    int node = blockIdx.x * 4 + wave;
    int f = lane < 48 ? lane : 0;
    if (lane < 48) tbuf[wave][lane] = bf2f(h[node * 48 + lane]);
    float v = -INFINITY;
    {
        const float4* t4 = (const float4*)tbuf[wave];
        float s = b1[f];
#pragma unroll
        for (int k4 = 0; k4 < 12; k4++) {
            float4 tv = t4[k4];
            s += tv.x * W1[(4 * k4 + 0) * 48 + f] + tv.y * W1[(4 * k4 + 1) * 48 + f]
               + tv.z * W1[(4 * k4 + 2) * 48 + f] + tv.w * W1[(4 * k4 + 3) * 48 + f];
        }
        if (lane < 48) v = s;
    }
    float m = v;
    for (int off = 32; off >= 1; off >>= 1) m = fmaxf(m, __shfl_xor(m, off));
    float ex = (lane < 48) ? expf(v - m) : 0.f;
    float sum = ex;
    for (int off = 32; off >= 1; off >>= 1) sum += __shfl_xor(sum, off);
    if (lane < 48) out[node * 48 + lane] = v - m - logf(sum);
}

extern "C" void kernel_launch(void* const* d_in, const int* in_sizes, int n_in,
                              void* d_out, int out_size, void* d_ws, size_t ws_size,
                              hipStream_t stream) {
    const float* x     = (const float*)d_in[0];
    const int*   ei    = (const int*)d_in[1];
    const float* W0    = (const float*)d_in[2];
    const float* b0    = (const float*)d_in[3];
    const float* convW = (const float*)d_in[4];
    const float* W1    = (const float*)d_in[5];
    const float* b1    = (const float*)d_in[6];
    float* out = (float*)d_out;
    const int* src = ei;            // edge_index[0]
    const int* dst = ei + N_EDGES;  // edge_index[1]

    char* ws = (char*)d_ws;
    size_t off = 0;
    u16* x0b    = (u16*)(ws + off);   off += (size_t)N_NODES * 48 * 2;     // 9.6 MB
    off = (off + 255) & ~(size_t)255;
    u16* hA     = (u16*)(ws + off);   off += (size_t)NPAD * 48 * 2;        // 9.6 MB (+pad rows)
    off = (off + 255) & ~(size_t)255;
    u16* hB     = (u16*)(ws + off);   off += (size_t)NPAD * 48 * 2;        // 9.6 MB (+pad rows)
    off = (off + 255) & ~(size_t)255;
    u32* edges  = (u32*)(ws + off);   off += (size_t)N_EDGES * 4;          // 6.4 MB
    off = (off + 255) & ~(size_t)255;
    int* blockhist = (int*)(ws + off); off += (size_t)SORTB * NBKT * 4;    // 786 KB
    off = (off + 255) & ~(size_t)255;
    int* bktptr = (int*)(ws + off);   off += (size_t)(NBKT + 1) * 4;
    off = (off + 255) & ~(size_t)255;
    int* tot    = (int*)(ws + off);   off += (size_t)NBKT * 4;

    lin0_k<<<18750, 256, 0, stream>>>(x, W0, b0, x0b, hA);
    histA_k<<<SORTB, 256, 0, stream>>>(src, dst, blockhist);
    scanS1_k<<<NBKT / 256, 256, 0, stream>>>(blockhist, tot);
    scanS2_k<<<1, 256, 0, stream>>>(tot, bktptr);
    scatB_k<<<SORTB, 256, 0, stream>>>(src, dst, blockhist, bktptr, edges);

    const float betas[4] = { logf(1.5f), logf(1.25f), logf(7.f / 6.f), logf(1.125f) };

    u16* hin = hA; u16* hout = hB;
    for (int l = 0; l < 4; l++) {
        layer3_k<<<NRANGE, 512, 0, stream>>>(hin, edges, bktptr, x0b, convW + l * 2304, betas[l], hout);
        u16* tmp = hin; hin = hout; hout = tmp;
    }
    final_k<<<25000, 256, 0, stream>>>(hin, W1, b1, out);
}